// Round 2
// baseline (723.583 us; speedup 1.0000x reference)
//
#include <hip/hip_runtime.h>
#include <hip/hip_bf16.h>

// ExactAttention: B=2 N=2048 H=16 D=128, fp32 in [b,n,h,d], out fp32 [b,h,n,d], NO 1/sqrt(d).
// Flash-attention forward, fp16 MFMA 16x16x32 (fp32 accum) — fp16 (not bf16) for 4x lower
// quantization error on the unscaled logits (|S| up to ~50).
// Block = 256 thr (4 waves). Each block: 64 q-rows of one (b,h); wave owns 16 q-rows.
// KV tiles of 64 staged in LDS (K as [kv][d] f16 swizzled, V transposed [d][kv] f16 swizzled).
// P goes through per-wave LDS tile to re-layout S-frag -> A-frag.

constexpr int Bb = 2, Nn = 2048, Hh = 16, Dd = 128;
constexpr int BQ = 64;    // q rows per block
constexpr int BKV = 64;   // kv tile
constexpr int ROWSTR = Hh * Dd;  // 2048 floats between consecutive n

typedef __attribute__((ext_vector_type(8))) _Float16 f16x8;
typedef __attribute__((ext_vector_type(4))) float f32x4;

__device__ __forceinline__ unsigned short f2h(float f) {
  union { _Float16 h; unsigned short u; } v;
  v.h = (_Float16)f;
  return v.u;
}

__global__ __launch_bounds__(256, 2) void attn_fwd_kernel(
    const float* __restrict__ Q, const float* __restrict__ K,
    const float* __restrict__ V, float* __restrict__ O) {
  // LDS: K tile [64][128] f16 swizzled (16KB), Vt tile [128][64] f16 swizzled (16KB),
  // P per-wave [16][64] f16 swizzled (4x2KB). Total 40KB.
  __shared__ alignas(16) short Klds[BKV * Dd];
  __shared__ alignas(16) short Vtlds[Dd * BKV];
  __shared__ alignas(16) short Plds[4][16 * BKV];

  const int tid = threadIdx.x;
  const int wave = tid >> 6;
  const int lane = tid & 63;
  const int g = lane >> 4;      // 0..3
  const int l15 = lane & 15;    // 0..15

  const int qb = blockIdx.x & 31;          // N/BQ = 32
  const int h = (blockIdx.x >> 5) & 15;
  const int b = blockIdx.x >> 9;

  const float* Qb = Q + ((size_t)b * Nn * Hh + h) * Dd;
  const float* Kb = K + ((size_t)b * Nn * Hh + h) * Dd;
  const float* Vb = V + ((size_t)b * Nn * Hh + h) * Dd;
  float* Ob = O + ((size_t)(b * Hh + h) * Nn) * Dd;

  // ---- Q fragments (held in regs all kernel). A-frag: row=l15, k = 8g+e per 32-wide chunk.
  const int qrow = qb * BQ + wave * 16 + l15;
  f16x8 qf[4];
  {
    const float* qp = Qb + (size_t)qrow * ROWSTR;
#pragma unroll
    for (int c = 0; c < 4; ++c) {
      const float* p = qp + c * 32 + g * 8;
      float4 a = *(const float4*)(p);
      float4 bb = *(const float4*)(p + 4);
      f16x8 t;
      t[0] = (_Float16)a.x;  t[1] = (_Float16)a.y;
      t[2] = (_Float16)a.z;  t[3] = (_Float16)a.w;
      t[4] = (_Float16)bb.x; t[5] = (_Float16)bb.y;
      t[6] = (_Float16)bb.z; t[7] = (_Float16)bb.w;
      qf[c] = t;
    }
  }

  f32x4 acc[8];
#pragma unroll
  for (int i = 0; i < 8; ++i) acc[i] = (f32x4){0.f, 0.f, 0.f, 0.f};
  float m_run[4], l_run[4];
#pragma unroll
  for (int r = 0; r < 4; ++r) { m_run[r] = -INFINITY; l_run[r] = 0.f; }

  char* KB = (char*)Klds;
  char* VB = (char*)Vtlds;
  char* PB = (char*)(Plds[wave]);

  for (int kt = 0; kt < Nn / BKV; ++kt) {
    const int kv0 = kt * BKV;
    __syncthreads();  // everyone done reading previous tile

    // ---- stage K tile: [64 kv][128 d] fp32 -> f16 LDS, swizzle byte ^= ((kv&7)<<4)
#pragma unroll
    for (int i = 0; i < 8; ++i) {
      int id = i * 256 + tid;          // 0..2047
      int f = id & 31;                 // float4 index along d
      int kv = id >> 5;                // 0..63
      const float* p = Kb + (size_t)(kv0 + kv) * ROWSTR + f * 4;
      float4 a = *(const float4*)p;
      unsigned long long pk =
          (unsigned long long)f2h(a.x) | ((unsigned long long)f2h(a.y) << 16) |
          ((unsigned long long)f2h(a.z) << 32) | ((unsigned long long)f2h(a.w) << 48);
      int byte = kv * 256 + ((f * 8) ^ ((kv & 7) << 4));
      *(unsigned long long*)(KB + byte) = pk;
    }
    // ---- stage V tile transposed: Vt[d][kv], swizzle byte ^= ((d&7)<<4)
#pragma unroll
    for (int i = 0; i < 8; ++i) {
      int id = i * 256 + tid;          // 0..2047
      int d = id & 127;
      int kq = id >> 7;                // kv quad 0..15
      const float* p = Vb + (size_t)(kv0 + kq * 4) * ROWSTR + d;
      float v0 = p[0];
      float v1 = p[ROWSTR];
      float v2 = p[2 * ROWSTR];
      float v3 = p[3 * ROWSTR];
      unsigned long long pk =
          (unsigned long long)f2h(v0) | ((unsigned long long)f2h(v1) << 16) |
          ((unsigned long long)f2h(v2) << 32) | ((unsigned long long)f2h(v3) << 48);
      int byte = d * 128 + ((kq * 8) ^ ((d & 7) << 4));
      *(unsigned long long*)(VB + byte) = pk;
    }
    __syncthreads();

    // ---- S = Q K^T : 4 col-tiles of 16 kv, accumulate over 4 d-chunks of 32
    f32x4 s[4];
#pragma unroll
    for (int t = 0; t < 4; ++t) {
      f32x4 cacc = (f32x4){0.f, 0.f, 0.f, 0.f};
      int row = t * 16 + l15;  // kv row in tile
#pragma unroll
      for (int c = 0; c < 4; ++c) {
        int byte = row * 256 + (((c * 64) + g * 16) ^ ((row & 7) << 4));
        f16x8 kf = *(const f16x8*)(KB + byte);
        cacc = __builtin_amdgcn_mfma_f32_16x16x32_f16(qf[c], kf, cacc, 0, 0, 0);
      }
      s[t] = cacc;  // S[q=4g+r][kv=t*16+l15]
    }

    // ---- online softmax (per r: q-row 4g+r; reduce over 16 lanes of the group)
#pragma unroll
    for (int r = 0; r < 4; ++r) {
      float mx = fmaxf(fmaxf(s[0][r], s[1][r]), fmaxf(s[2][r], s[3][r]));
      mx = fmaxf(mx, __shfl_xor(mx, 1));
      mx = fmaxf(mx, __shfl_xor(mx, 2));
      mx = fmaxf(mx, __shfl_xor(mx, 4));
      mx = fmaxf(mx, __shfl_xor(mx, 8));
      float mn = fmaxf(m_run[r], mx);
      float e = exp2f((m_run[r] - mn) * 1.44269504f);
      float ps = 0.f;
#pragma unroll
      for (int t = 0; t < 4; ++t) {
        float pv = exp2f((s[t][r] - mn) * 1.44269504f);
        s[t][r] = pv;
        ps += pv;
      }
      ps += __shfl_xor(ps, 1);
      ps += __shfl_xor(ps, 2);
      ps += __shfl_xor(ps, 4);
      ps += __shfl_xor(ps, 8);
      l_run[r] = l_run[r] * e + ps;
      m_run[r] = mn;
#pragma unroll
      for (int dt = 0; dt < 8; ++dt) acc[dt][r] *= e;
    }

    // ---- P (f16) -> per-wave LDS [q16][kv64], swizzle byte ^= ((q&7)<<4)
#pragma unroll
    for (int t = 0; t < 4; ++t) {
#pragma unroll
      for (int r = 0; r < 4; ++r) {
        int q = g * 4 + r;
        int kv = t * 16 + l15;
        int byte = q * 128 + ((kv * 2) ^ ((q & 7) << 4));
        *(unsigned short*)(PB + byte) = f2h(s[t][r]);
      }
    }

    // ---- PV: out[q][d] += P[q][kv] * V[kv][d]
#pragma unroll
    for (int c2 = 0; c2 < 2; ++c2) {
      int pbyte = l15 * 128 + (((c2 * 64) + g * 16) ^ ((l15 & 7) << 4));
      f16x8 pf = *(const f16x8*)(PB + pbyte);
#pragma unroll
      for (int dt = 0; dt < 8; ++dt) {
        int d = dt * 16 + l15;
        int vbyte = d * 128 + (((c2 * 64) + g * 16) ^ ((d & 7) << 4));
        f16x8 vf = *(const f16x8*)(VB + vbyte);
        acc[dt] = __builtin_amdgcn_mfma_f32_16x16x32_f16(pf, vf, acc[dt], 0, 0, 0);
      }
    }
  }

  // ---- epilogue: divide by row sum, write out [b][h][q][d]
  const int qout = qb * BQ + wave * 16;
#pragma unroll
  for (int r = 0; r < 4; ++r) {
    float inv = 1.0f / l_run[r];
    float* op = Ob + (size_t)(qout + g * 4 + r) * Dd + l15;
#pragma unroll
    for (int dt = 0; dt < 8; ++dt) {
      op[dt * 16] = acc[dt][r] * inv;
    }
  }
}

extern "C" void kernel_launch(void* const* d_in, const int* in_sizes, int n_in,
                              void* d_out, int out_size, void* d_ws, size_t ws_size,
                              hipStream_t stream) {
  const float* Q = (const float*)d_in[0];
  const float* K = (const float*)d_in[1];
  const float* V = (const float*)d_in[2];
  float* O = (float*)d_out;
  dim3 grid(Bb * Hh * (Nn / BQ));  // 2*16*32 = 1024 blocks
  attn_fwd_kernel<<<grid, 256, 0, stream>>>(Q, K, V, O);
}

// Round 3
// 274.805 us; speedup vs baseline: 2.6331x; 2.6331x over previous
//
#include <hip/hip_runtime.h>
#include <hip/hip_bf16.h>
#include <stdint.h>

// ExactAttention: B=2 N=2048 H=16 D=128, fp32 in [b,n,h,d], out fp32 [b,h,n,d], NO 1/sqrt(d).
// Round 3: two-phase plan.
//  Kernel A1: Q,K fp32->f16 elementwise (layout kept [b,n,h,d]).
//  Kernel A2: V fp32->f16 transposed to [b,h,d,n] (LDS tile transpose).
//  Kernel B : flash attention, f16 MFMA 16x16x32, BQ=256 (8 waves x 32q),
//             KV tiles (64) double-buffered in LDS via global_load_lds(16B)
//             with pre-swizzled per-lane SOURCE addresses (LDS linear,
//             swizzle ^((row&7)<<4) applied at source and at ds_read).
// Fallback: if ws_size < 50.3MB, run the verified round-2 kernel.

constexpr int Bb = 2, Nn = 2048, Hh = 16, Dd = 128;
constexpr int ROWSTR = Hh * Dd;             // 2048 floats between consecutive n
constexpr size_t TEN_ELEMS = (size_t)Bb * Nn * Hh * Dd;   // 8388608
constexpr size_t WS_NEED = 3 * TEN_ELEMS * 2;             // 50331648 bytes

typedef __attribute__((ext_vector_type(8))) _Float16 f16x8;
typedef __attribute__((ext_vector_type(4))) float f32x4;

__device__ __forceinline__ unsigned short f2h(float f) {
  union { _Float16 h; unsigned short u; } v;
  v.h = (_Float16)f;
  return v.u;
}

__device__ __forceinline__ void gload_lds16(const void* g, void* l) {
  __builtin_amdgcn_global_load_lds(
      (const __attribute__((address_space(1))) unsigned int*)g,
      (__attribute__((address_space(3))) unsigned int*)l, 16, 0, 0);
}

// ---------------- Kernel A1: elementwise convert Q,K -> f16 ----------------
__global__ __launch_bounds__(512) void conv_qk(
    const float* __restrict__ Q, const float* __restrict__ K,
    _Float16* __restrict__ Qf, _Float16* __restrict__ Kf) {
  size_t id = (size_t)blockIdx.x * 512 + threadIdx.x;
  const float* src;
  _Float16* dst;
  size_t e;
  if (id < TEN_ELEMS / 8) { src = Q; dst = Qf; e = id * 8; }
  else { src = K; dst = Kf; e = (id - TEN_ELEMS / 8) * 8; }
  float4 a = *(const float4*)(src + e);
  float4 b = *(const float4*)(src + e + 4);
  f16x8 t;
  t[0] = (_Float16)a.x; t[1] = (_Float16)a.y; t[2] = (_Float16)a.z; t[3] = (_Float16)a.w;
  t[4] = (_Float16)b.x; t[5] = (_Float16)b.y; t[6] = (_Float16)b.z; t[7] = (_Float16)b.w;
  *(f16x8*)(dst + e) = t;
}

// ---------------- Kernel A2: V -> f16 transposed [b,h,d,n] ----------------
__global__ __launch_bounds__(256) void conv_v(
    const float* __restrict__ V, _Float16* __restrict__ Vt) {
  __shared__ alignas(16) short T[128 * 72];  // rows of 144B (64 n + 8 pad f16)
  const int tid = threadIdx.x;
  const int bid = blockIdx.x;
  const int bh = bid >> 5;            // 0..31
  const int n0 = (bid & 31) * 64;
  const int h = bh & 15, b = bh >> 4;
  const float* src = V + (((size_t)b * Nn + n0) * Hh + h) * Dd;
#pragma unroll
  for (int it = 0; it < 8; ++it) {
    int id = it * 256 + tid;
    int f = id & 31, n = id >> 5;     // f: float4 along d, n: 0..63
    float4 a = *(const float4*)(src + (size_t)n * ROWSTR + f * 4);
    T[(4 * f + 0) * 72 + n] = (short)f2h(a.x);
    T[(4 * f + 1) * 72 + n] = (short)f2h(a.y);
    T[(4 * f + 2) * 72 + n] = (short)f2h(a.z);
    T[(4 * f + 3) * 72 + n] = (short)f2h(a.w);
  }
  __syncthreads();
  _Float16* dst = Vt + (size_t)bh * Dd * Nn + n0;
#pragma unroll
  for (int it = 0; it < 4; ++it) {
    int cid = it * 256 + tid;
    int d = cid >> 3, nc = cid & 7;
    f16x8 v = *(const f16x8*)((const char*)T + d * 144 + nc * 16);
    *(f16x8*)(dst + (size_t)d * Nn + nc * 8) = v;
  }
}

// ---------------- Kernel B: flash attention on f16 ----------------
// grid = 256 blocks (8 qb x 32 bh), 512 thr (8 waves), each wave 32 q-rows.
// LDS: Kbuf[2] 16KB @0/16384, Vtbuf[2] 16KB @32768/49152, P 8x4KB @65536. 96KB.
__global__ __launch_bounds__(512, 2) void attn_f16(
    const _Float16* __restrict__ Qf, const _Float16* __restrict__ Kf,
    const _Float16* __restrict__ Vt, float* __restrict__ O) {
  __shared__ alignas(16) short LDS[98304 / 2];
  char* base = (char*)LDS;

  const int tid = threadIdx.x;
  const int wave = tid >> 6;
  const int lane = tid & 63;
  const int g = (lane >> 4) & 3;
  const int l15 = lane & 15;

  // XCD swizzle: dispatch-index raw -> logical wg so each head's 8 q-blocks
  // share an XCD (raw%8 == XCD id on 8-XCD MI355X; 256 = 8*32 exactly).
  const int raw = blockIdx.x;
  const int wg = (raw & 7) * 32 + (raw >> 3);
  const int qb = wg & 7;
  const int bh = wg >> 3;
  const int h = bh & 15, b = bh >> 4;
  const int q0 = qb * 256;

  const char* K0 = (const char*)Kf + ((size_t)b * Nn * Hh + h) * 256;  // row n stride 4096B
  const char* Q0 = (const char*)Qf + ((size_t)b * Nn * Hh + h) * 256;
  const char* V0 = (const char*)Vt + (size_t)bh * Dd * Nn * 2;         // row d stride 4096B
  float* Ob = O + (size_t)bh * Nn * Dd;

  // ---- Q fragments: 2 q-subtiles x 4 k-chunks, A-frag row=l15, k=8g+e.
  const int wq0 = q0 + wave * 32;
  f16x8 qf[2][4];
#pragma unroll
  for (int qs = 0; qs < 2; ++qs) {
    const char* qp = Q0 + (size_t)(wq0 + qs * 16 + l15) * 4096;
#pragma unroll
    for (int c = 0; c < 4; ++c)
      qf[qs][c] = *(const f16x8*)(qp + c * 64 + g * 16);
  }

  f32x4 acc[2][8];
#pragma unroll
  for (int qs = 0; qs < 2; ++qs)
#pragma unroll
    for (int dt = 0; dt < 8; ++dt) acc[qs][dt] = (f32x4){0.f, 0.f, 0.f, 0.f};
  float m_run[2][4], l_run[2][4];
#pragma unroll
  for (int qs = 0; qs < 2; ++qs)
#pragma unroll
    for (int r = 0; r < 4; ++r) { m_run[qs][r] = -INFINITY; l_run[qs][r] = 0.f; }

  char* PB = base + 65536 + wave * 4096;  // per-wave P [32q][64kv] f16, swz ^((q&7)<<4)

  // STAGE tile kt into buffer bufsel: 2 K issues + 2 V issues per thread.
  auto STAGE = [&](int bufsel, int kt) {
    const int kv0 = kt * 64;
    char* kdst = base + bufsel * 16384;
    char* vdst = base + 32768 + bufsel * 16384;
#pragma unroll
    for (int i = 0; i < 2; ++i) {
      int ob = i * 8192 + wave * 1024;      // wave-uniform LDS offset
      int o = ob + lane * 16;               // this lane's 16B slot
      int kv = o >> 8, ir = o & 255;        // K tile row 256B
      gload_lds16(K0 + (size_t)(kv0 + kv) * 4096 + (ir ^ ((kv & 7) << 4)), kdst + ob);
      int d = o >> 7, ir2 = o & 127;        // Vt tile row 128B
      gload_lds16(V0 + (size_t)d * 4096 + kv0 * 2 + (ir2 ^ ((d & 7) << 4)), vdst + ob);
    }
  };

  STAGE(0, 0);
  __syncthreads();
  int cur = 0;

  for (int kt = 0; kt < Nn / 64; ++kt) {
    if (kt < Nn / 64 - 1) STAGE(cur ^ 1, kt + 1);
    const char* KB = base + cur * 16384;
    const char* VB = base + 32768 + cur * 16384;

    // ---- QK^T: S[2qs][4 t4] , K-frag shared across q-subtiles
    f32x4 s[2][4];
#pragma unroll
    for (int qs = 0; qs < 2; ++qs)
#pragma unroll
      for (int t4 = 0; t4 < 4; ++t4) s[qs][t4] = (f32x4){0.f, 0.f, 0.f, 0.f};
#pragma unroll
    for (int t4 = 0; t4 < 4; ++t4) {
      const int row = t4 * 16 + l15;
      const int ro = row * 256;
      const int swz = (row & 7) << 4;
#pragma unroll
      for (int c = 0; c < 4; ++c) {
        f16x8 kf = *(const f16x8*)(KB + ro + ((c * 64 + g * 16) ^ swz));
        s[0][t4] = __builtin_amdgcn_mfma_f32_16x16x32_f16(qf[0][c], kf, s[0][t4], 0, 0, 0);
        s[1][t4] = __builtin_amdgcn_mfma_f32_16x16x32_f16(qf[1][c], kf, s[1][t4], 0, 0, 0);
      }
    }

    // ---- online softmax + P write (per q-subtile)
#pragma unroll
    for (int qs = 0; qs < 2; ++qs) {
#pragma unroll
      for (int r = 0; r < 4; ++r) {
        float mx = fmaxf(fmaxf(s[qs][0][r], s[qs][1][r]), fmaxf(s[qs][2][r], s[qs][3][r]));
        mx = fmaxf(mx, __shfl_xor(mx, 1));
        mx = fmaxf(mx, __shfl_xor(mx, 2));
        mx = fmaxf(mx, __shfl_xor(mx, 4));
        mx = fmaxf(mx, __shfl_xor(mx, 8));
        float mn = fmaxf(m_run[qs][r], mx);
        float e = exp2f((m_run[qs][r] - mn) * 1.44269504f);
        float ps = 0.f;
#pragma unroll
        for (int t4 = 0; t4 < 4; ++t4) {
          float pv = exp2f((s[qs][t4][r] - mn) * 1.44269504f);
          s[qs][t4][r] = pv;
          ps += pv;
        }
        ps += __shfl_xor(ps, 1);
        ps += __shfl_xor(ps, 2);
        ps += __shfl_xor(ps, 4);
        ps += __shfl_xor(ps, 8);
        l_run[qs][r] = l_run[qs][r] * e + ps;
        m_run[qs][r] = mn;
#pragma unroll
        for (int dt = 0; dt < 8; ++dt) acc[qs][dt][r] *= e;
      }
#pragma unroll
      for (int t4 = 0; t4 < 4; ++t4)
#pragma unroll
        for (int r = 0; r < 4; ++r) {
          int qq = qs * 16 + 4 * g + r;
          int byte = qq * 128 + (((t4 * 16 + l15) * 2) ^ ((qq & 7) << 4));
          *(unsigned short*)(PB + byte) = f2h(s[qs][t4][r]);
        }
    }

    // ---- PV: V-frag shared across q-subtiles
#pragma unroll
    for (int c2 = 0; c2 < 2; ++c2) {
      f16x8 pf0 = *(const f16x8*)(PB + l15 * 128 + ((c2 * 64 + g * 16) ^ ((l15 & 7) << 4)));
      f16x8 pf1 = *(const f16x8*)(PB + (16 + l15) * 128 + ((c2 * 64 + g * 16) ^ ((l15 & 7) << 4)));
#pragma unroll
      for (int dt = 0; dt < 8; ++dt) {
        const int d = dt * 16 + l15;
        f16x8 vf = *(const f16x8*)(VB + d * 128 + ((c2 * 64 + g * 16) ^ ((d & 7) << 4)));
        acc[0][dt] = __builtin_amdgcn_mfma_f32_16x16x32_f16(pf0, vf, acc[0][dt], 0, 0, 0);
        acc[1][dt] = __builtin_amdgcn_mfma_f32_16x16x32_f16(pf1, vf, acc[1][dt], 0, 0, 0);
      }
    }
    __syncthreads();
    cur ^= 1;
  }

  // ---- epilogue
#pragma unroll
  for (int qs = 0; qs < 2; ++qs)
#pragma unroll
    for (int r = 0; r < 4; ++r) {
      float inv = 1.0f / l_run[qs][r];
      float* op = Ob + (size_t)(wq0 + qs * 16 + 4 * g + r) * Dd + l15;
#pragma unroll
      for (int dt = 0; dt < 8; ++dt) op[dt * 16] = acc[qs][dt][r] * inv;
    }
}

// ---------------- Fallback: verified round-2 kernel (fp32 direct) ----------------
__global__ __launch_bounds__(256, 2) void attn_fwd_kernel(
    const float* __restrict__ Q, const float* __restrict__ K,
    const float* __restrict__ V, float* __restrict__ O) {
  __shared__ alignas(16) short Klds[64 * Dd];
  __shared__ alignas(16) short Vtlds[Dd * 64];
  __shared__ alignas(16) short Plds[4][16 * 64];

  const int tid = threadIdx.x;
  const int wave = tid >> 6;
  const int lane = tid & 63;
  const int g = lane >> 4;
  const int l15 = lane & 15;

  const int qb = blockIdx.x & 31;
  const int h = (blockIdx.x >> 5) & 15;
  const int b = blockIdx.x >> 9;

  const float* Qb = Q + ((size_t)b * Nn * Hh + h) * Dd;
  const float* Kb = K + ((size_t)b * Nn * Hh + h) * Dd;
  const float* Vb = V + ((size_t)b * Nn * Hh + h) * Dd;
  float* Ob = O + ((size_t)(b * Hh + h) * Nn) * Dd;

  const int qrow = qb * 64 + wave * 16 + l15;
  f16x8 qf[4];
  {
    const float* qp = Qb + (size_t)qrow * ROWSTR;
#pragma unroll
    for (int c = 0; c < 4; ++c) {
      const float* p = qp + c * 32 + g * 8;
      float4 a = *(const float4*)(p);
      float4 bb = *(const float4*)(p + 4);
      f16x8 t;
      t[0] = (_Float16)a.x;  t[1] = (_Float16)a.y;
      t[2] = (_Float16)a.z;  t[3] = (_Float16)a.w;
      t[4] = (_Float16)bb.x; t[5] = (_Float16)bb.y;
      t[6] = (_Float16)bb.z; t[7] = (_Float16)bb.w;
      qf[c] = t;
    }
  }

  f32x4 acc[8];
#pragma unroll
  for (int i = 0; i < 8; ++i) acc[i] = (f32x4){0.f, 0.f, 0.f, 0.f};
  float m_run[4], l_run[4];
#pragma unroll
  for (int r = 0; r < 4; ++r) { m_run[r] = -INFINITY; l_run[r] = 0.f; }

  char* KB = (char*)Klds;
  char* VB = (char*)Vtlds;
  char* PB = (char*)(Plds[wave]);

  for (int kt = 0; kt < Nn / 64; ++kt) {
    const int kv0 = kt * 64;
    __syncthreads();
#pragma unroll
    for (int i = 0; i < 8; ++i) {
      int id = i * 256 + tid;
      int f = id & 31;
      int kv = id >> 5;
      const float* p = Kb + (size_t)(kv0 + kv) * ROWSTR + f * 4;
      float4 a = *(const float4*)p;
      unsigned long long pk =
          (unsigned long long)f2h(a.x) | ((unsigned long long)f2h(a.y) << 16) |
          ((unsigned long long)f2h(a.z) << 32) | ((unsigned long long)f2h(a.w) << 48);
      int byte = kv * 256 + ((f * 8) ^ ((kv & 7) << 4));
      *(unsigned long long*)(KB + byte) = pk;
    }
#pragma unroll
    for (int i = 0; i < 8; ++i) {
      int id = i * 256 + tid;
      int d = id & 127;
      int kq = id >> 7;
      const float* p = Vb + (size_t)(kv0 + kq * 4) * ROWSTR + d;
      float v0 = p[0];
      float v1 = p[ROWSTR];
      float v2 = p[2 * ROWSTR];
      float v3 = p[3 * ROWSTR];
      unsigned long long pk =
          (unsigned long long)f2h(v0) | ((unsigned long long)f2h(v1) << 16) |
          ((unsigned long long)f2h(v2) << 32) | ((unsigned long long)f2h(v3) << 48);
      int byte = d * 128 + ((kq * 8) ^ ((d & 7) << 4));
      *(unsigned long long*)(VB + byte) = pk;
    }
    __syncthreads();

    f32x4 s[4];
#pragma unroll
    for (int t = 0; t < 4; ++t) {
      f32x4 cacc = (f32x4){0.f, 0.f, 0.f, 0.f};
      int row = t * 16 + l15;
#pragma unroll
      for (int c = 0; c < 4; ++c) {
        int byte = row * 256 + (((c * 64) + g * 16) ^ ((row & 7) << 4));
        f16x8 kf = *(const f16x8*)(KB + byte);
        cacc = __builtin_amdgcn_mfma_f32_16x16x32_f16(qf[c], kf, cacc, 0, 0, 0);
      }
      s[t] = cacc;
    }

#pragma unroll
    for (int r = 0; r < 4; ++r) {
      float mx = fmaxf(fmaxf(s[0][r], s[1][r]), fmaxf(s[2][r], s[3][r]));
      mx = fmaxf(mx, __shfl_xor(mx, 1));
      mx = fmaxf(mx, __shfl_xor(mx, 2));
      mx = fmaxf(mx, __shfl_xor(mx, 4));
      mx = fmaxf(mx, __shfl_xor(mx, 8));
      float mn = fmaxf(m_run[r], mx);
      float e = exp2f((m_run[r] - mn) * 1.44269504f);
      float ps = 0.f;
#pragma unroll
      for (int t = 0; t < 4; ++t) {
        float pv = exp2f((s[t][r] - mn) * 1.44269504f);
        s[t][r] = pv;
        ps += pv;
      }
      ps += __shfl_xor(ps, 1);
      ps += __shfl_xor(ps, 2);
      ps += __shfl_xor(ps, 4);
      ps += __shfl_xor(ps, 8);
      l_run[r] = l_run[r] * e + ps;
      m_run[r] = mn;
#pragma unroll
      for (int dt = 0; dt < 8; ++dt) acc[dt][r] *= e;
    }

#pragma unroll
    for (int t = 0; t < 4; ++t)
#pragma unroll
      for (int r = 0; r < 4; ++r) {
        int q = g * 4 + r;
        int kv = t * 16 + l15;
        int byte = q * 128 + ((kv * 2) ^ ((q & 7) << 4));
        *(unsigned short*)(PB + byte) = f2h(s[t][r]);
      }

#pragma unroll
    for (int c2 = 0; c2 < 2; ++c2) {
      int pbyte = l15 * 128 + (((c2 * 64) + g * 16) ^ ((l15 & 7) << 4));
      f16x8 pf = *(const f16x8*)(PB + pbyte);
#pragma unroll
      for (int dt = 0; dt < 8; ++dt) {
        int d = dt * 16 + l15;
        int vbyte = d * 128 + (((c2 * 64) + g * 16) ^ ((d & 7) << 4));
        f16x8 vf = *(const f16x8*)(VB + vbyte);
        acc[dt] = __builtin_amdgcn_mfma_f32_16x16x32_f16(pf, vf, acc[dt], 0, 0, 0);
      }
    }
  }

  const int qout = qb * 64 + wave * 16;
#pragma unroll
  for (int r = 0; r < 4; ++r) {
    float inv = 1.0f / l_run[r];
    float* op = Ob + (size_t)(qout + g * 4 + r) * Dd + l15;
#pragma unroll
    for (int dt = 0; dt < 8; ++dt) {
      op[dt * 16] = acc[dt][r] * inv;
    }
  }
}

extern "C" void kernel_launch(void* const* d_in, const int* in_sizes, int n_in,
                              void* d_out, int out_size, void* d_ws, size_t ws_size,
                              hipStream_t stream) {
  const float* Q = (const float*)d_in[0];
  const float* K = (const float*)d_in[1];
  const float* V = (const float*)d_in[2];
  float* O = (float*)d_out;

  if (ws_size >= WS_NEED) {
    _Float16* Qf = (_Float16*)d_ws;
    _Float16* Kf = Qf + TEN_ELEMS;
    _Float16* Vt = Kf + TEN_ELEMS;
    conv_qk<<<dim3(4096), 512, 0, stream>>>(Q, K, Qf, Kf);
    conv_v<<<dim3(1024), 256, 0, stream>>>(V, Vt);
    attn_f16<<<dim3(256), 512, 0, stream>>>(Qf, Kf, Vt, O);
  } else {
    attn_fwd_kernel<<<dim3(1024), 256, 0, stream>>>(Q, K, V, O);
  }
}

// Round 5
// 222.026 us; speedup vs baseline: 3.2590x; 1.2377x over previous
//
#include <hip/hip_runtime.h>
#include <hip/hip_bf16.h>
#include <stdint.h>

// ExactAttention: B=2 N=2048 H=16 D=128, fp32 in [b,n,h,d], out fp32 [b,h,n,d], NO 1/sqrt(d).
// Round 5: 32x32x16 swapped-QK^T in-register-softmax flash attention (m214-style).
//  conv_k: K fp32->f16 elementwise.  conv_v: V fp32->f16 transposed [b,h,d,n].
//  attn32: 4 waves x 32q (128q/block), KVBLK=64 double-buffered via global_load_lds(16B)
//          with pre-swizzled source; S^T=mfma(K,Q) -> softmax fully lane-local (q=lane&31);
//          P packed in-register (cvt_pkrtz + shfl_xor(32)); O^T=mfma(V^T,P^T) q-lane-local.
// Fallback (ws too small): verified round-2 kernel.

constexpr int Bb = 2, Nn = 2048, Hh = 16, Dd = 128;
constexpr int ROWSTR = Hh * Dd;                          // 2048 floats between consecutive n
constexpr size_t TEN = (size_t)Bb * Nn * Hh * Dd;        // 8388608
constexpr size_t WS_NEED = 2 * TEN * 2;                  // Kf16 + Vt f16 = 33.5MB

typedef __attribute__((ext_vector_type(8))) _Float16 f16x8;
typedef __attribute__((ext_vector_type(2))) __fp16 fp16x2;
typedef __attribute__((ext_vector_type(4))) float f32x4;
typedef __attribute__((ext_vector_type(16))) float f32x16;

__device__ __forceinline__ unsigned short f2h(float f) {
  union { _Float16 h; unsigned short u; } v;
  v.h = (_Float16)f;
  return v.u;
}

__device__ __forceinline__ unsigned pk2(float a, float b) {
  union { fp16x2 h; unsigned u; } v;
  v.h = __builtin_amdgcn_cvt_pkrtz(a, b);
  return v.u;
}

__device__ __forceinline__ void gload_lds16(const void* g, void* l) {
  __builtin_amdgcn_global_load_lds(
      (const __attribute__((address_space(1))) unsigned int*)g,
      (__attribute__((address_space(3))) unsigned int*)l, 16, 0, 0);
}

__device__ __forceinline__ f32x16 zero16() {
  f32x16 z;
#pragma unroll
  for (int i = 0; i < 16; ++i) z[i] = 0.f;
  return z;
}

// ---------------- conv_k: K fp32 -> f16, layout kept [b,n,h,d] ----------------
__global__ __launch_bounds__(512) void conv_k(
    const float* __restrict__ K, _Float16* __restrict__ Kf) {
  size_t id = (size_t)blockIdx.x * 512 + threadIdx.x;
  size_t e = id * 8;
  float4 a = *(const float4*)(K + e);
  float4 b = *(const float4*)(K + e + 4);
  f16x8 t;
  t[0] = (_Float16)a.x; t[1] = (_Float16)a.y; t[2] = (_Float16)a.z; t[3] = (_Float16)a.w;
  t[4] = (_Float16)b.x; t[5] = (_Float16)b.y; t[6] = (_Float16)b.z; t[7] = (_Float16)b.w;
  *(f16x8*)(Kf + e) = t;
}

// ---------------- conv_v: V fp32 -> f16 transposed [b,h,d,n] ----------------
__global__ __launch_bounds__(256) void conv_v(
    const float* __restrict__ V, _Float16* __restrict__ Vt) {
  __shared__ alignas(16) short T[128 * 72];  // rows of 144B (64 n + 8 pad f16)
  const int tid = threadIdx.x;
  const int bid = blockIdx.x;
  const int bh = bid >> 5;            // 0..31
  const int n0 = (bid & 31) * 64;
  const int h = bh & 15, b = bh >> 4;
  const float* src = V + (((size_t)b * Nn + n0) * Hh + h) * Dd;
#pragma unroll
  for (int it = 0; it < 8; ++it) {
    int id = it * 256 + tid;
    int f = id & 31, n = id >> 5;
    float4 a = *(const float4*)(src + (size_t)n * ROWSTR + f * 4);
    T[(4 * f + 0) * 72 + n] = (short)f2h(a.x);
    T[(4 * f + 1) * 72 + n] = (short)f2h(a.y);
    T[(4 * f + 2) * 72 + n] = (short)f2h(a.z);
    T[(4 * f + 3) * 72 + n] = (short)f2h(a.w);
  }
  __syncthreads();
  _Float16* dst = Vt + (size_t)bh * Dd * Nn + n0;
#pragma unroll
  for (int it = 0; it < 4; ++it) {
    int cid = it * 256 + tid;
    int d = cid >> 3, nc = cid & 7;
    f16x8 v = *(const f16x8*)((const char*)T + d * 144 + nc * 16);
    *(f16x8*)(dst + (size_t)d * Nn + nc * 8) = v;
  }
}

// ---------------- attn32: 32x32x16 swapped-QK flash attention ----------------
// grid 512 (16 qb x 32 bh), 256 thr (4 waves x 32 q-rows). LDS 64KB:
// K dbuf @0/@16384 ([64kv][256B] swz ^((kv&15)<<4)), Vt dbuf @32768/@49152
// ([128d][128B] swz ^((d&7)<<4)).
__global__ __launch_bounds__(256, 2) void attn32(
    const float* __restrict__ Q, const _Float16* __restrict__ Kf,
    const _Float16* __restrict__ Vt, float* __restrict__ O) {
  __shared__ alignas(16) char base[65536];

  const int tid = threadIdx.x;
  const int wave = tid >> 6;
  const int lane = tid & 63;
  const int l31 = lane & 31;
  const int hi = lane >> 5;

  // XCD swizzle: 512 = 8 XCD x 64; chunk per XCD = 4 heads x 16 q-blocks (KV L2-resident).
  const int raw = blockIdx.x;
  const int wg = (raw & 7) * 64 + (raw >> 3);
  const int qb = wg & 15;
  const int bh = wg >> 4;
  const int h = bh & 15, b = bh >> 4;

  const char* K0 = (const char*)Kf + ((size_t)b * Nn * Hh + h) * 256;   // n-row stride 4096B
  const char* V0 = (const char*)Vt + (size_t)bh * Dd * Nn * 2;          // d-row stride 4096B
  const float* Q0 = Q + ((size_t)b * Nn * Hh + h) * 128;                // fp32, n-row stride 8192B
  float* Ob = O + (size_t)bh * Nn * Dd;

  const int wq0 = qb * 128 + wave * 32;
  const int kswz = (l31 & 15) << 4;   // K-read swizzle (same for both kv-halves)
  const int vswz = (l31 & 7) << 4;    // V-read swizzle (same for all dt)

  // STAGE tile kt into buffer buf: 4 K + 4 V global_load_lds(16B) per thread.
  auto STAGE = [&](int buf, int kt) {
    const size_t kv0 = (size_t)kt * 64;
    char* kd = base + buf * 16384;
    char* vd = base + 32768 + buf * 16384;
    const char* ks = K0 + kv0 * 4096;
    const char* vs = V0 + kv0 * 2;
#pragma unroll
    for (int i = 0; i < 4; ++i) {
      int ob = i * 4096 + wave * 1024;   // wave-uniform LDS dest
      int o = ob + lane * 16;            // this lane's linear slot
      int kv = o >> 8, ck = o & 255;
      gload_lds16(ks + (size_t)kv * 4096 + (ck ^ ((kv & 15) << 4)), kd + ob);
      int d = o >> 7, cv = o & 127;
      gload_lds16(vs + (size_t)d * 4096 + (cv ^ ((d & 7) << 4)), vd + ob);
    }
  };

  STAGE(0, 0);

  // Q fragments (B-operand of swapped QK^T): qf[c] = Q[q=wq0+l31][d=16c+8hi..+7], c=0..7.
  f16x8 qf[8];
  {
    const float* qp = Q0 + (size_t)(wq0 + l31) * ROWSTR;
#pragma unroll
    for (int c = 0; c < 8; ++c) {
      const float* p = qp + c * 16 + hi * 8;
      float4 a = *(const float4*)p;
      float4 bb = *(const float4*)(p + 4);
      f16x8 t;
      t[0] = (_Float16)a.x;  t[1] = (_Float16)a.y;
      t[2] = (_Float16)a.z;  t[3] = (_Float16)a.w;
      t[4] = (_Float16)bb.x; t[5] = (_Float16)bb.y;
      t[6] = (_Float16)bb.z; t[7] = (_Float16)bb.w;
      qf[c] = t;
    }
  }

  f32x16 acc[4];
#pragma unroll
  for (int dt = 0; dt < 4; ++dt) acc[dt] = zero16();
  float m_run = -INFINITY, l_run = 0.f;

  __syncthreads();
  int cur = 0;

  for (int kt = 0; kt < Nn / 64; ++kt) {
    if (kt < Nn / 64 - 1) STAGE(cur ^ 1, kt + 1);
    const char* KB = base + cur * 16384;
    const char* VB = base + 32768 + cur * 16384;

    // ---- S^T = mfma(K, Q): s[sub] covers kv = 32sub + crow(r,hi); q = l31.
    f32x16 s[2];
    s[0] = zero16();
    s[1] = zero16();
#pragma unroll
    for (int c = 0; c < 8; ++c) {
      const int colc = 32 * c + 16 * hi;
      f16x8 k0 = *(const f16x8*)(KB + l31 * 256 + (colc ^ kswz));
      f16x8 k1 = *(const f16x8*)(KB + (l31 + 32) * 256 + (colc ^ kswz));
      s[0] = __builtin_amdgcn_mfma_f32_32x32x16_f16(k0, qf[c], s[0], 0, 0, 0);
      s[1] = __builtin_amdgcn_mfma_f32_32x32x16_f16(k1, qf[c], s[1], 0, 0, 0);
    }

    // ---- online softmax, fully lane-local (q = l31); partner lane = lane^32.
    float mx = s[0][0];
#pragma unroll
    for (int r = 1; r < 16; ++r) mx = fmaxf(mx, s[0][r]);
#pragma unroll
    for (int r = 0; r < 16; ++r) mx = fmaxf(mx, s[1][r]);
    mx = fmaxf(mx, __shfl_xor(mx, 32));

    // defer-max (T13): rescale only when tile max grew past threshold.
    if (!__all(mx <= m_run + 8.0f)) {
      float mn = fmaxf(m_run, mx);
      float e = exp2f((m_run - mn) * 1.44269504f);
      l_run *= e;
#pragma unroll
      for (int dt = 0; dt < 4; ++dt)
#pragma unroll
        for (int r = 0; r < 16; ++r) acc[dt][r] *= e;
      m_run = mn;
    }
    float ps = 0.f;
#pragma unroll
    for (int sub = 0; sub < 2; ++sub)
#pragma unroll
      for (int r = 0; r < 16; ++r) {
        float pv = exp2f((s[sub][r] - m_run) * 1.44269504f);
        s[sub][r] = pv;
        ps += pv;
      }
    ps += __shfl_xor(ps, 32);
    l_run += ps;

    // ---- pack P -> pa[ks] (B-operand of PV): lane needs kv = 16ks + 8hi + e.
    // own r=8kb+f maps to kv=16ks+f (hi_src=hi); partner supplies the other quad.
    f16x8 pa[4];
#pragma unroll
    for (int ks = 0; ks < 4; ++ks) {
      const int sub = ks >> 1, kb = ks & 1;
      float v0 = s[sub][8 * kb + 0], v1 = s[sub][8 * kb + 1];
      float v2 = s[sub][8 * kb + 2], v3 = s[sub][8 * kb + 3];
      float v4 = s[sub][8 * kb + 4], v5 = s[sub][8 * kb + 5];
      float v6 = s[sub][8 * kb + 6], v7 = s[sub][8 * kb + 7];
      unsigned uA0 = pk2(v0, v1), uA1 = pk2(v2, v3);
      unsigned uB0 = pk2(v4, v5), uB1 = pk2(v6, v7);
      unsigned r0 = (unsigned)__shfl_xor((int)(hi ? uA0 : uB0), 32);
      unsigned r1 = (unsigned)__shfl_xor((int)(hi ? uA1 : uB1), 32);
      union { unsigned u[4]; f16x8 v; } t;
      t.u[0] = hi ? r0 : uA0;
      t.u[1] = hi ? r1 : uA1;
      t.u[2] = hi ? uB0 : r0;
      t.u[3] = hi ? uB1 : r1;
      pa[ks] = t.v;
    }

    // ---- O^T += mfma(V^T, P^T): acc[dt] = O^T[d=32dt+crow(r,hi)][q=l31].
#pragma unroll
    for (int dt = 0; dt < 4; ++dt) {
      const char* vrow = VB + (32 * dt + l31) * 128;
#pragma unroll
      for (int ks = 0; ks < 4; ++ks) {
        f16x8 vf = *(const f16x8*)(vrow + ((32 * ks + 16 * hi) ^ vswz));
        acc[dt] = __builtin_amdgcn_mfma_f32_32x32x16_f16(vf, pa[ks], acc[dt], 0, 0, 0);
      }
    }

    __syncthreads();
    cur ^= 1;
  }

  // ---- epilogue: q = wq0+l31 is lane-local; scalar stores (L2 merges rows).
  const float invl = 1.0f / l_run;
  float* orow = Ob + (size_t)(wq0 + l31) * Dd;
#pragma unroll
  for (int dt = 0; dt < 4; ++dt)
#pragma unroll
    for (int r = 0; r < 16; ++r) {
      int d = 32 * dt + (r & 3) + 8 * (r >> 2) + 4 * hi;
      orow[d] = acc[dt][r] * invl;
    }
}

// ---------------- Fallback: verified round-2 kernel (fp32 direct) ----------------
__global__ __launch_bounds__(256, 2) void attn_fwd_kernel(
    const float* __restrict__ Q, const float* __restrict__ K,
    const float* __restrict__ V, float* __restrict__ O) {
  __shared__ alignas(16) short Klds[64 * Dd];
  __shared__ alignas(16) short Vtlds[Dd * 64];
  __shared__ alignas(16) short Plds[4][16 * 64];

  const int tid = threadIdx.x;
  const int wave = tid >> 6;
  const int lane = tid & 63;
  const int g = lane >> 4;
  const int l15 = lane & 15;

  const int qb = blockIdx.x & 31;
  const int h = (blockIdx.x >> 5) & 15;
  const int b = blockIdx.x >> 9;

  const float* Qb = Q + ((size_t)b * Nn * Hh + h) * Dd;
  const float* Kb = K + ((size_t)b * Nn * Hh + h) * Dd;
  const float* Vb = V + ((size_t)b * Nn * Hh + h) * Dd;
  float* Ob = O + ((size_t)(b * Hh + h) * Nn) * Dd;

  const int qrow = qb * 64 + wave * 16 + l15;
  f16x8 qf[4];
  {
    const float* qp = Qb + (size_t)qrow * ROWSTR;
#pragma unroll
    for (int c = 0; c < 4; ++c) {
      const float* p = qp + c * 32 + g * 8;
      float4 a = *(const float4*)(p);
      float4 bb = *(const float4*)(p + 4);
      f16x8 t;
      t[0] = (_Float16)a.x;  t[1] = (_Float16)a.y;
      t[2] = (_Float16)a.z;  t[3] = (_Float16)a.w;
      t[4] = (_Float16)bb.x; t[5] = (_Float16)bb.y;
      t[6] = (_Float16)bb.z; t[7] = (_Float16)bb.w;
      qf[c] = t;
    }
  }

  f32x4 acc[8];
#pragma unroll
  for (int i = 0; i < 8; ++i) acc[i] = (f32x4){0.f, 0.f, 0.f, 0.f};
  float m_run[4], l_run[4];
#pragma unroll
  for (int r = 0; r < 4; ++r) { m_run[r] = -INFINITY; l_run[r] = 0.f; }

  char* KB = (char*)Klds;
  char* VB = (char*)Vtlds;
  char* PB = (char*)(Plds[wave]);

  for (int kt = 0; kt < Nn / 64; ++kt) {
    const int kv0 = kt * 64;
    __syncthreads();
#pragma unroll
    for (int i = 0; i < 8; ++i) {
      int id = i * 256 + tid;
      int f = id & 31;
      int kv = id >> 5;
      const float* p = Kb + (size_t)(kv0 + kv) * ROWSTR + f * 4;
      float4 a = *(const float4*)p;
      unsigned long long pk =
          (unsigned long long)f2h(a.x) | ((unsigned long long)f2h(a.y) << 16) |
          ((unsigned long long)f2h(a.z) << 32) | ((unsigned long long)f2h(a.w) << 48);
      int byte = kv * 256 + ((f * 8) ^ ((kv & 7) << 4));
      *(unsigned long long*)(KB + byte) = pk;
    }
#pragma unroll
    for (int i = 0; i < 8; ++i) {
      int id = i * 256 + tid;
      int d = id & 127;
      int kq = id >> 7;
      const float* p = Vb + (size_t)(kv0 + kq * 4) * ROWSTR + d;
      float v0 = p[0];
      float v1 = p[ROWSTR];
      float v2 = p[2 * ROWSTR];
      float v3 = p[3 * ROWSTR];
      unsigned long long pk =
          (unsigned long long)f2h(v0) | ((unsigned long long)f2h(v1) << 16) |
          ((unsigned long long)f2h(v2) << 32) | ((unsigned long long)f2h(v3) << 48);
      int byte = d * 128 + ((kq * 8) ^ ((d & 7) << 4));
      *(unsigned long long*)(VB + byte) = pk;
    }
    __syncthreads();

    f32x4 s[4];
#pragma unroll
    for (int t = 0; t < 4; ++t) {
      f32x4 cacc = (f32x4){0.f, 0.f, 0.f, 0.f};
      int row = t * 16 + l15;
#pragma unroll
      for (int c = 0; c < 4; ++c) {
        int byte = row * 256 + (((c * 64) + g * 16) ^ ((row & 7) << 4));
        f16x8 kf = *(const f16x8*)(KB + byte);
        cacc = __builtin_amdgcn_mfma_f32_16x16x32_f16(qf[c], kf, cacc, 0, 0, 0);
      }
      s[t] = cacc;
    }

#pragma unroll
    for (int r = 0; r < 4; ++r) {
      float mx = fmaxf(fmaxf(s[0][r], s[1][r]), fmaxf(s[2][r], s[3][r]));
      mx = fmaxf(mx, __shfl_xor(mx, 1));
      mx = fmaxf(mx, __shfl_xor(mx, 2));
      mx = fmaxf(mx, __shfl_xor(mx, 4));
      mx = fmaxf(mx, __shfl_xor(mx, 8));
      float mn = fmaxf(m_run[r], mx);
      float e = exp2f((m_run[r] - mn) * 1.44269504f);
      float ps = 0.f;
#pragma unroll
      for (int t = 0; t < 4; ++t) {
        float pv = exp2f((s[t][r] - mn) * 1.44269504f);
        s[t][r] = pv;
        ps += pv;
      }
      ps += __shfl_xor(ps, 1);
      ps += __shfl_xor(ps, 2);
      ps += __shfl_xor(ps, 4);
      ps += __shfl_xor(ps, 8);
      l_run[r] = l_run[r] * e + ps;
      m_run[r] = mn;
#pragma unroll
      for (int dt = 0; dt < 8; ++dt) acc[dt][r] *= e;
    }

#pragma unroll
    for (int t = 0; t < 4; ++t)
#pragma unroll
      for (int r = 0; r < 4; ++r) {
        int q = g * 4 + r;
        int kv = t * 16 + l15;
        int byte = q * 128 + ((kv * 2) ^ ((q & 7) << 4));
        *(unsigned short*)(PB + byte) = f2h(s[t][r]);
      }

#pragma unroll
    for (int c2 = 0; c2 < 2; ++c2) {
      int pbyte = l15 * 128 + (((c2 * 64) + g * 16) ^ ((l15 & 7) << 4));
      f16x8 pf = *(const f16x8*)(PB + pbyte);
#pragma unroll
      for (int dt = 0; dt < 8; ++dt) {
        int d = dt * 16 + l15;
        int vbyte = d * 128 + (((c2 * 64) + g * 16) ^ ((d & 7) << 4));
        f16x8 vf = *(const f16x8*)(VB + vbyte);
        acc[dt] = __builtin_amdgcn_mfma_f32_16x16x32_f16(pf, vf, acc[dt], 0, 0, 0);
      }
    }
  }

  const int qout = qb * 64 + wave * 16;
#pragma unroll
  for (int r = 0; r < 4; ++r) {
    float inv = 1.0f / l_run[r];
    float* op = Ob + (size_t)(qout + g * 4 + r) * Dd + l15;
#pragma unroll
    for (int dt = 0; dt < 8; ++dt) {
      op[dt * 16] = acc[dt][r] * inv;
    }
  }
}

extern "C" void kernel_launch(void* const* d_in, const int* in_sizes, int n_in,
                              void* d_out, int out_size, void* d_ws, size_t ws_size,
                              hipStream_t stream) {
  const float* Q = (const float*)d_in[0];
  const float* K = (const float*)d_in[1];
  const float* V = (const float*)d_in[2];
  float* O = (float*)d_out;

  if (ws_size >= WS_NEED) {
    _Float16* Kf = (_Float16*)d_ws;
    _Float16* Vt = Kf + TEN;
    conv_k<<<dim3(TEN / 8 / 512), 512, 0, stream>>>(K, Kf);
    conv_v<<<dim3(1024), 256, 0, stream>>>(V, Vt);
    attn32<<<dim3(512), 256, 0, stream>>>(Q, Kf, Vt, O);
  } else {
    attn_fwd_kernel<<<dim3(1024), 256, 0, stream>>>(Q, K, V, O);
  }
}